// Round 10
// baseline (233.429 us; speedup 1.0000x reference)
//
#include <hip/hip_runtime.h>
#include <hip/hip_bf16.h>

typedef __attribute__((ext_vector_type(4))) float floatx4;
typedef __attribute__((ext_vector_type(8))) short short8;
typedef __attribute__((ext_vector_type(8))) unsigned short ushortx8;

#define K1 2048
#define N1 1024
#define K2 1024
#define N2 1024

__device__ __forceinline__ unsigned short f2bf(float f) {
  __hip_bfloat16 h = __float2bfloat16(f);
  return __builtin_bit_cast(unsigned short, h);
}

__device__ __forceinline__ void gload_lds16(const void* g, void* l) {
  __builtin_amdgcn_global_load_lds(
      (__attribute__((address_space(1))) void*)const_cast<void*>(g),
      (__attribute__((address_space(3))) void*)l, 16, 0, 0);
}

__global__ void cvt_bf16_kernel(const float* __restrict__ src,
                                unsigned short* __restrict__ dst, int n4) {
  int i = blockIdx.x * blockDim.x + threadIdx.x;
  if (i >= n4) return;
  float4 f = reinterpret_cast<const float4*>(src)[i];
  ushort4 o;
  o.x = f2bf(f.x); o.y = f2bf(f.y); o.z = f2bf(f.z); o.w = f2bf(f.w);
  reinterpret_cast<ushort4*>(dst)[i] = o;
}

// GEMM1 with fused gather: h = gelu(bf16(tok[idx]) @ W1^T + b1).
// 128x128 tile, BK=64, 4 waves (2x2), 64 KB LDS -> 2 blocks/CU (stall hiding).
// bn = p&7: XCD x owns one bn column -> W1 panel (512 KB) L2-resident; the 8
// XCDs sweep the same tok stripe concurrently -> L3 serves 7/8 of gathers.
__global__ __launch_bounds__(256, 2) void gemm1_fused_kernel(
    const int* __restrict__ idxs, const float* __restrict__ tok,
    const unsigned short* __restrict__ W1b, const float* __restrict__ b1,
    unsigned short* __restrict__ hout) {
  __shared__ unsigned short Asub[2][8192];
  __shared__ unsigned short Bsub[2][8192];
  const int t = threadIdx.x;
  const int p = blockIdx.x;
  const int brow0 = (p >> 3) * 128, bcol0 = (p & 7) * 128;
  const int lane = t & 63, w = t >> 6;
  const int wm = w >> 1, wn = w & 1;  // per-wave C: 64x64
  const int fr = lane & 15, kg2 = lane >> 4;

  // staging: rows r = (t>>3)+32q, chunk cg = (t&7)^(r&7) (32q&7==0 -> q-const)
  const int srow = t >> 3;
  const int cg = (t & 7) ^ (srow & 7);
  const float* aqf[4];
  const unsigned short* bq[4];
#pragma unroll
  for (int q = 0; q < 4; ++q) {
    const int r = srow + 32 * q;
    aqf[q] = tok + (size_t)idxs[brow0 + r] * K1 + cg * 8;
    bq[q] = W1b + (size_t)(bcol0 + r) * K1 + cg * 8;
  }
  const int t8 = t * 8;  // linear LDS dest: chunk r*8+(t&7) == t + 256q

  floatx4 acc[4][4] = {};
  constexpr int NT = K1 / 64;

  float4 av[4][2];
  auto loadA = [&](int k0) {
#pragma unroll
    for (int q = 0; q < 4; ++q) {
      av[q][0] = *reinterpret_cast<const float4*>(aqf[q] + k0);
      av[q][1] = *reinterpret_cast<const float4*>(aqf[q] + k0 + 4);
    }
  };
  auto writeA = [&](int d) {
#pragma unroll
    for (int q = 0; q < 4; ++q) {
      ushortx8 u;
      u[0] = f2bf(av[q][0].x); u[1] = f2bf(av[q][0].y);
      u[2] = f2bf(av[q][0].z); u[3] = f2bf(av[q][0].w);
      u[4] = f2bf(av[q][1].x); u[5] = f2bf(av[q][1].y);
      u[6] = f2bf(av[q][1].z); u[7] = f2bf(av[q][1].w);
      *reinterpret_cast<ushortx8*>(&Asub[d][t8 + q * 2048]) = u;
    }
  };
  auto issueB = [&](int d, int k0) {
#pragma unroll
    for (int q = 0; q < 4; ++q)
      gload_lds16(bq[q] + k0, &Bsub[d][t8 + q * 2048]);
  };
  auto computeKS = [&](int cur, int ks) {
    const int sl = ((ks * 4 + kg2) ^ (fr & 7)) * 8;
    short8 bf[4];
#pragma unroll
    for (int j = 0; j < 4; ++j)
      bf[j] = *(const short8*)&Bsub[cur][(wn * 64 + j * 16 + fr) * 64 + sl];
    __builtin_amdgcn_s_setprio(1);
#pragma unroll
    for (int i = 0; i < 4; ++i) {
      const short8 af = *(const short8*)&Asub[cur][(wm * 64 + i * 16 + fr) * 64 + sl];
#pragma unroll
      for (int j = 0; j < 4; ++j)
        acc[i][j] = __builtin_amdgcn_mfma_f32_16x16x32_bf16(af, bf[j], acc[i][j], 0, 0, 0);
    }
    __builtin_amdgcn_s_setprio(0);
  };

  // prologue: stage tile 0
  loadA(0);
  issueB(0, 0);
  writeA(0);  // compiler auto-waits the av loads
  asm volatile("s_waitcnt vmcnt(0) lgkmcnt(0)\ns_barrier" ::: "memory");

#pragma unroll 1
  for (int tt = 0; tt < NT; ++tt) {
    const int cur = tt & 1;
    const int nbuf = cur ^ 1;
    const bool pf = (tt + 1 < NT);
    const int nk = (tt + 1) * 64;
    if (pf) {
      loadA(nk);         // 8 fp32x4 reg loads in flight over ks0
      issueB(nbuf, nk);  // 4 gload_lds in flight until boundary
    }
    computeKS(cur, 0);
    if (pf) writeA(nbuf);  // cvt + ds_write under ks1's window
    computeKS(cur, 1);
    asm volatile("s_waitcnt vmcnt(0) lgkmcnt(0)\ns_barrier" ::: "memory");
  }

  // epilogue: bias + exact GELU -> bf16. C/D: col=lane&15, row=(lane>>4)*4+r
  const int er0 = brow0 + wm * 64 + kg2 * 4;
  const int ec0 = bcol0 + wn * 64 + fr;
#pragma unroll
  for (int j = 0; j < 4; ++j) {
    const float bv = b1[ec0 + j * 16];
#pragma unroll
    for (int i = 0; i < 4; ++i)
#pragma unroll
      for (int r = 0; r < 4; ++r) {
        float v = acc[i][j][r] + bv;
        v = 0.5f * v * (1.0f + erff(v * 0.70710678118654752f));
        hout[(size_t)(er0 + i * 16 + r) * N1 + (ec0 + j * 16)] = f2bf(v);
      }
  }
}

// GEMM2: out = h @ W2^T + b2 (fp32 out). Same 128x128/2-blocks-per-CU shape.
__global__ __launch_bounds__(256, 2) void gemm2_kernel(
    const unsigned short* __restrict__ A, const unsigned short* __restrict__ Bw,
    const float* __restrict__ bias, float* __restrict__ out) {
  __shared__ unsigned short Asub[2][8192];
  __shared__ unsigned short Bsub[2][8192];
  const int t = threadIdx.x;
  const int p = blockIdx.x;
  const int brow0 = (p >> 3) * 128, bcol0 = (p & 7) * 128;
  const int lane = t & 63, w = t >> 6;
  const int wm = w >> 1, wn = w & 1;
  const int fr = lane & 15, kg2 = lane >> 4;

  const int srow = t >> 3;
  const int cg = (t & 7) ^ (srow & 7);
  const unsigned short* aq[4];
  const unsigned short* bq[4];
#pragma unroll
  for (int q = 0; q < 4; ++q) {
    const int r = srow + 32 * q;
    aq[q] = A + (size_t)(brow0 + r) * K2 + cg * 8;
    bq[q] = Bw + (size_t)(bcol0 + r) * K2 + cg * 8;
  }
  const int t8 = t * 8;

  floatx4 acc[4][4] = {};
  constexpr int NT = K2 / 64;

  auto stage = [&](int d, int k0) {
#pragma unroll
    for (int q = 0; q < 4; ++q) {
      gload_lds16(aq[q] + k0, &Asub[d][t8 + q * 2048]);
      gload_lds16(bq[q] + k0, &Bsub[d][t8 + q * 2048]);
    }
  };
  auto compute = [&](int cur) {
#pragma unroll
    for (int ks = 0; ks < 2; ++ks) {
      const int sl = ((ks * 4 + kg2) ^ (fr & 7)) * 8;
      short8 bf[4];
#pragma unroll
      for (int j = 0; j < 4; ++j)
        bf[j] = *(const short8*)&Bsub[cur][(wn * 64 + j * 16 + fr) * 64 + sl];
      __builtin_amdgcn_s_setprio(1);
#pragma unroll
      for (int i = 0; i < 4; ++i) {
        const short8 af = *(const short8*)&Asub[cur][(wm * 64 + i * 16 + fr) * 64 + sl];
#pragma unroll
        for (int j = 0; j < 4; ++j)
          acc[i][j] = __builtin_amdgcn_mfma_f32_16x16x32_bf16(af, bf[j], acc[i][j], 0, 0, 0);
      }
      __builtin_amdgcn_s_setprio(0);
    }
  };

  stage(0, 0);
#pragma unroll 1
  for (int it = 0; it < NT - 1; ++it) {
    const int cur = it & 1;
    stage(cur ^ 1, (it + 1) * 64);
    asm volatile("s_waitcnt vmcnt(8)\ns_barrier" ::: "memory");
    compute(cur);
    asm volatile("s_waitcnt lgkmcnt(0)\ns_barrier" ::: "memory");
  }
  asm volatile("s_waitcnt vmcnt(0)\ns_barrier" ::: "memory");
  compute((NT - 1) & 1);

  const int er0 = brow0 + wm * 64 + kg2 * 4;
  const int ec0 = bcol0 + wn * 64 + fr;
#pragma unroll
  for (int j = 0; j < 4; ++j) {
    const float bv = bias[ec0 + j * 16];
#pragma unroll
    for (int i = 0; i < 4; ++i)
#pragma unroll
      for (int r = 0; r < 4; ++r)
        out[(size_t)(er0 + i * 16 + r) * N2 + (ec0 + j * 16)] = acc[i][j][r] + bv;
  }
}

extern "C" void kernel_launch(void* const* d_in, const int* in_sizes, int n_in,
                              void* d_out, int out_size, void* d_ws, size_t ws_size,
                              hipStream_t stream) {
  const int* idxs = (const int*)d_in[0];
  const float* tok = (const float*)d_in[1];
  const float* W1 = (const float*)d_in[2];
  const float* b1 = (const float*)d_in[3];
  const float* W2 = (const float*)d_in[4];
  const float* b2 = (const float*)d_in[5];
  float* out = (float*)d_out;

  unsigned short* W1b = (unsigned short*)d_ws;                          // 4 MB
  unsigned short* W2b = (unsigned short*)((char*)d_ws + (4u << 20));    // 2 MB
  unsigned short* hbuf = (unsigned short*)((char*)d_ws + (6u << 20));   // 32 MB

  cvt_bf16_kernel<<<2048, 256, 0, stream>>>(W1, W1b, 524288);
  cvt_bf16_kernel<<<1024, 256, 0, stream>>>(W2, W2b, 262144);
  gemm1_fused_kernel<<<1024, 256, 0, stream>>>(idxs, tok, W1b, b1, hbuf);
  gemm2_kernel<<<1024, 256, 0, stream>>>(hbuf, W2b, b2, out);
}

// Round 11
// 197.065 us; speedup vs baseline: 1.1845x; 1.1845x over previous
//
#include <hip/hip_runtime.h>
#include <hip/hip_bf16.h>

typedef __attribute__((ext_vector_type(4))) float floatx4;
typedef __attribute__((ext_vector_type(8))) short short8;
typedef __attribute__((ext_vector_type(8))) unsigned short ushortx8;

#define K1 2048
#define N1 1024
#define K2 1024
#define N2 1024

__device__ __forceinline__ unsigned short f2bf(float f) {
  __hip_bfloat16 h = __float2bfloat16(f);
  return __builtin_bit_cast(unsigned short, h);
}

__device__ __forceinline__ void gload_lds16(const void* g, void* l) {
  __builtin_amdgcn_global_load_lds(
      (__attribute__((address_space(1))) void*)const_cast<void*>(g),
      (__attribute__((address_space(3))) void*)l, 16, 0, 0);
}

__global__ void cvt_bf16_kernel(const float* __restrict__ src,
                                unsigned short* __restrict__ dst, int n4) {
  int i = blockIdx.x * blockDim.x + threadIdx.x;
  if (i >= n4) return;
  float4 f = reinterpret_cast<const float4*>(src)[i];
  ushort4 o;
  o.x = f2bf(f.x); o.y = f2bf(f.y); o.z = f2bf(f.z); o.w = f2bf(f.w);
  reinterpret_cast<ushort4*>(dst)[i] = o;
}

// GEMM1 + fused gather: h = gelu(bf16(tok[idx]) @ W1^T + b1).
// 256x256 tile, BK=32, 8 waves, 4-deep LDS ring, counted vmcnt (never 0
// mid-loop). A: fp32->reg (held 2 iters)->cvt->ds_write into PADDED [256][36]
// LDS (conflict-free, no swizzle needed since reg-staged). B: gload_lds into
// [256 rows][4 slots] with XOR slot = kg2^((fr>>1)&3) (2-way = free).
__global__ __launch_bounds__(512, 2) void gemm1_fused_kernel(
    const int* __restrict__ idxs, const float* __restrict__ tok,
    const unsigned short* __restrict__ W1b, const float* __restrict__ b1,
    unsigned short* __restrict__ hout) {
  __shared__ unsigned short As[4][9216];  // [256][36] padded rows
  __shared__ unsigned short Bs[4][8192];  // [256][4 slots][8]
  const int t = threadIdx.x;
  const int p = blockIdx.x;
  const int bid = (p & 7) * 32 + (p >> 3);  // XCD owns contiguous bm range
  const int bm = bid >> 2, bn = bid & 3;
  const int brow0 = bm * 256, bcol0 = bn * 256;
  const int lane = t & 63, w = t >> 6;
  const int wm = w >> 2, wn = w & 3;  // per-wave C: 128x64
  const int fr = lane & 15, kg2 = lane >> 4;
  const int slB = (kg2 ^ ((fr >> 1) & 3)) * 8;  // swizzled B slot (shorts)

  // A staging: row ar = t>>1, fp32 cols [(t&1)*16, +16) -> chunks (t&1)*2,+1
  const int ar = t >> 1;
  const float* aptr = tok + (size_t)idxs[brow0 + ar] * K1 + (t & 1) * 16;
  const int awr = ar * 36 + (t & 1) * 16;  // LDS shorts offset

  // B staging: instr j covers row j*128+(t>>2); src chunk (t&3)^((t>>3)&3)
  const unsigned short* bptr[2];
#pragma unroll
  for (int j = 0; j < 2; ++j)
    bptr[j] = W1b + (size_t)(bcol0 + j * 128 + (t >> 2)) * K1 +
              ((t & 3) ^ ((t >> 3) & 3)) * 8;
  const int t8 = t * 8;

  floatx4 acc[8][4] = {};
  constexpr int NT = K1 / 32;  // 64

  float4 av[2][4];
  auto loadAv = [&](float4* dst, int k0) {
#pragma unroll
    for (int q = 0; q < 4; ++q)
      dst[q] = *reinterpret_cast<const float4*>(aptr + k0 + q * 4);
  };
  auto writeAv = [&](int d, const float4* src) {
#pragma unroll
    for (int j = 0; j < 2; ++j) {
      ushortx8 u;
      u[0] = f2bf(src[2 * j].x); u[1] = f2bf(src[2 * j].y);
      u[2] = f2bf(src[2 * j].z); u[3] = f2bf(src[2 * j].w);
      u[4] = f2bf(src[2 * j + 1].x); u[5] = f2bf(src[2 * j + 1].y);
      u[6] = f2bf(src[2 * j + 1].z); u[7] = f2bf(src[2 * j + 1].w);
      *reinterpret_cast<ushortx8*>(&As[d][awr + j * 8]) = u;
    }
  };
  auto gloadB = [&](int d, int k0) {
#pragma unroll
    for (int j = 0; j < 2; ++j)
      gload_lds16(bptr[j] + k0, &Bs[d][j * 4096 + t8]);
  };
  auto compute = [&](int cur) {
    short8 bf[4];
#pragma unroll
    for (int j = 0; j < 4; ++j)
      bf[j] = *(const short8*)&Bs[cur][(wn * 64 + j * 16 + fr) * 32 + slB];
    __builtin_amdgcn_s_setprio(1);
#pragma unroll
    for (int i = 0; i < 8; ++i) {
      const short8 af =
          *(const short8*)&As[cur][(wm * 128 + i * 16 + fr) * 36 + kg2 * 8];
#pragma unroll
      for (int j = 0; j < 4; ++j)
        acc[i][j] = __builtin_amdgcn_mfma_f32_16x16x32_bf16(af, bf[j], acc[i][j], 0, 0, 0);
    }
    __builtin_amdgcn_s_setprio(0);
  };

  // prologue: A tile0 direct; B tiles 0,1,2; av <- A tiles 1,2
  {
    float4 tv[4];
    loadAv(tv, 0);
    gloadB(0, 0); gloadB(1, 32); gloadB(2, 64);
    loadAv(av[0], 32);
    loadAv(av[1], 64);
    writeAv(0, tv);  // compiler waits tv's loads
    asm volatile("s_waitcnt vmcnt(0) lgkmcnt(0)\ns_barrier" ::: "memory");
  }

  // iter tt: 6 vm ops (4 loadAv + 2 gloadB). B(tile tt) last-issued at iter
  // tt-3 -> 12 newer ops at iter-tt top -> vmcnt(12); taper 6 -> 0 at tail.
#pragma unroll 2
  for (int tt = 0; tt < NT; ++tt) {
    if (tt < NT - 2)
      asm volatile("s_waitcnt vmcnt(12) lgkmcnt(0)\ns_barrier" ::: "memory");
    else if (tt == NT - 2)
      asm volatile("s_waitcnt vmcnt(6) lgkmcnt(0)\ns_barrier" ::: "memory");
    else
      asm volatile("s_waitcnt vmcnt(0) lgkmcnt(0)\ns_barrier" ::: "memory");
    if (tt + 1 < NT) writeAv((tt + 1) & 3, av[tt & 1]);  // A for next tile
    if (tt + 3 < NT) {
      loadAv(av[tt & 1], (tt + 3) * 32);  // av free: just written from
      gloadB((tt + 3) & 3, (tt + 3) * 32);
    }
    compute(tt & 3);
  }

  // epilogue: C/D map col=lane&15, row=(lane>>4)*4+r
  const int er0 = brow0 + wm * 128 + kg2 * 4;
  const int ec0 = bcol0 + wn * 64 + fr;
#pragma unroll
  for (int j = 0; j < 4; ++j) {
    const float bv = b1[ec0 + j * 16];
#pragma unroll
    for (int i = 0; i < 8; ++i)
#pragma unroll
      for (int r = 0; r < 4; ++r) {
        float v = acc[i][j][r] + bv;
        v = 0.5f * v * (1.0f + erff(v * 0.70710678118654752f));
        hout[(size_t)(er0 + i * 16 + r) * N1 + (ec0 + j * 16)] = f2bf(v);
      }
  }
}

// GEMM2: out = h @ W2^T + b2 (fp32). Same 4-deep ring; A and B via gload_lds.
__global__ __launch_bounds__(512, 2) void gemm2_kernel(
    const unsigned short* __restrict__ hb, const unsigned short* __restrict__ W2b,
    const float* __restrict__ b2, float* __restrict__ out) {
  __shared__ unsigned short As[4][8192];
  __shared__ unsigned short Bs[4][8192];
  const int t = threadIdx.x;
  const int p = blockIdx.x;
  const int bid = (p & 7) * 32 + (p >> 3);
  const int bm = bid >> 2, bn = bid & 3;
  const int brow0 = bm * 256, bcol0 = bn * 256;
  const int lane = t & 63, w = t >> 6;
  const int wm = w >> 2, wn = w & 3;
  const int fr = lane & 15, kg2 = lane >> 4;
  const int slB = (kg2 ^ ((fr >> 1) & 3)) * 8;

  const unsigned short* aptr[2];
  const unsigned short* bptr[2];
#pragma unroll
  for (int j = 0; j < 2; ++j) {
    const int row = j * 128 + (t >> 2);
    const int cS = ((t & 3) ^ ((t >> 3) & 3)) * 8;
    aptr[j] = hb + (size_t)(brow0 + row) * K2 + cS;
    bptr[j] = W2b + (size_t)(bcol0 + row) * K2 + cS;
  }
  const int t8 = t * 8;

  floatx4 acc[8][4] = {};
  constexpr int NT = K2 / 32;  // 32

  auto stage = [&](int d, int k0) {
#pragma unroll
    for (int j = 0; j < 2; ++j) {
      gload_lds16(aptr[j] + k0, &As[d][j * 4096 + t8]);
      gload_lds16(bptr[j] + k0, &Bs[d][j * 4096 + t8]);
    }
  };
  auto compute = [&](int cur) {
    short8 bf[4];
#pragma unroll
    for (int j = 0; j < 4; ++j)
      bf[j] = *(const short8*)&Bs[cur][(wn * 64 + j * 16 + fr) * 32 + slB];
    __builtin_amdgcn_s_setprio(1);
#pragma unroll
    for (int i = 0; i < 8; ++i) {
      const short8 af =
          *(const short8*)&As[cur][(wm * 128 + i * 16 + fr) * 32 + slB];
#pragma unroll
      for (int j = 0; j < 4; ++j)
        acc[i][j] = __builtin_amdgcn_mfma_f32_16x16x32_bf16(af, bf[j], acc[i][j], 0, 0, 0);
    }
    __builtin_amdgcn_s_setprio(0);
  };

  stage(0, 0); stage(1, 32); stage(2, 64);
  asm volatile("s_waitcnt vmcnt(0) lgkmcnt(0)\ns_barrier" ::: "memory");

  // iter tt: 4 vm ops; tile tt's stage last-issued at iter tt-3 -> vmcnt(8).
#pragma unroll 1
  for (int tt = 0; tt < NT; ++tt) {
    if (tt < NT - 2)
      asm volatile("s_waitcnt vmcnt(8) lgkmcnt(0)\ns_barrier" ::: "memory");
    else if (tt == NT - 2)
      asm volatile("s_waitcnt vmcnt(4) lgkmcnt(0)\ns_barrier" ::: "memory");
    else
      asm volatile("s_waitcnt vmcnt(0) lgkmcnt(0)\ns_barrier" ::: "memory");
    if (tt + 3 < NT) stage((tt + 3) & 3, (tt + 3) * 32);
    compute(tt & 3);
  }

  const int er0 = brow0 + wm * 128 + kg2 * 4;
  const int ec0 = bcol0 + wn * 64 + fr;
#pragma unroll
  for (int j = 0; j < 4; ++j) {
    const float bv = b2[ec0 + j * 16];
#pragma unroll
    for (int i = 0; i < 8; ++i)
#pragma unroll
      for (int r = 0; r < 4; ++r)
        out[(size_t)(er0 + i * 16 + r) * N2 + (ec0 + j * 16)] = acc[i][j][r] + bv;
  }
}

extern "C" void kernel_launch(void* const* d_in, const int* in_sizes, int n_in,
                              void* d_out, int out_size, void* d_ws, size_t ws_size,
                              hipStream_t stream) {
  const int* idxs = (const int*)d_in[0];
  const float* tok = (const float*)d_in[1];
  const float* W1 = (const float*)d_in[2];
  const float* b1 = (const float*)d_in[3];
  const float* W2 = (const float*)d_in[4];
  const float* b2 = (const float*)d_in[5];
  float* out = (float*)d_out;

  unsigned short* W1b = (unsigned short*)d_ws;                          // 4 MB
  unsigned short* W2b = (unsigned short*)((char*)d_ws + (4u << 20));    // 2 MB
  unsigned short* hbuf = (unsigned short*)((char*)d_ws + (6u << 20));   // 32 MB

  cvt_bf16_kernel<<<2048, 256, 0, stream>>>(W1, W1b, 524288);
  cvt_bf16_kernel<<<1024, 256, 0, stream>>>(W2, W2b, 262144);
  gemm1_fused_kernel<<<256, 512, 0, stream>>>(idxs, tok, W1b, b1, hbuf);
  gemm2_kernel<<<256, 512, 0, stream>>>(hbuf, W2b, b2, out);
}

// Round 12
// 161.071 us; speedup vs baseline: 1.4492x; 1.2235x over previous
//
#include <hip/hip_runtime.h>
#include <hip/hip_bf16.h>

typedef __attribute__((ext_vector_type(4))) float floatx4;
typedef __attribute__((ext_vector_type(8))) short short8;
typedef __attribute__((ext_vector_type(8))) unsigned short ushortx8;

#define K1 2048
#define N1 1024
#define K2 1024
#define N2 1024

__device__ __forceinline__ unsigned short f2bf(float f) {
  __hip_bfloat16 h = __float2bfloat16(f);
  return __builtin_bit_cast(unsigned short, h);
}

__device__ __forceinline__ void gload_lds16(const void* g, void* l) {
  __builtin_amdgcn_global_load_lds(
      (__attribute__((address_space(1))) void*)const_cast<void*>(g),
      (__attribute__((address_space(3))) void*)l, 16, 0, 0);
}

__global__ void cvt_bf16_kernel(const float* __restrict__ src,
                                unsigned short* __restrict__ dst, int n4) {
  int i = blockIdx.x * blockDim.x + threadIdx.x;
  if (i >= n4) return;
  float4 f = reinterpret_cast<const float4*>(src)[i];
  ushort4 o;
  o.x = f2bf(f.x); o.y = f2bf(f.y); o.z = f2bf(f.z); o.w = f2bf(f.w);
  reinterpret_cast<ushort4*>(dst)[i] = o;
}

// GEMM1 + fused gather: h = gelu(bf16(tok[idx]) @ W1^T + b1).
// r9 geometry/body; ONLY change: counted-vmcnt boundaries (never drain to 0
// mid-loop). Issue order per iter: B0(1) at boundary -> loadA av(8) -> B123(3).
// writeA's implicit av-wait leaves B123 in flight; boundary waits vmcnt(1).
__global__ __launch_bounds__(512, 2) void gemm1_fused_kernel(
    const int* __restrict__ idxs, const float* __restrict__ tok,
    const unsigned short* __restrict__ W1b, const float* __restrict__ b1,
    unsigned short* __restrict__ hout) {
  __shared__ unsigned short Asub[2][16384];
  __shared__ unsigned short Bsub[2][16384];
  const int t = threadIdx.x;
  const int p = blockIdx.x;
  const int bid = (p & 7) * 32 + (p >> 3);  // XCD owns contiguous bm range
  const int bm = bid >> 2, bn = bid & 3;
  const int brow0 = bm * 256, bcol0 = bn * 256;
  const int lane = t & 63, w = t >> 6;
  const int wm = w >> 2, wn = w & 3;  // per-wave C: 128x64
  const int fr = lane & 15, kg2 = lane >> 4;

  // staging: row r = (t>>3)+64q, chunk cg = (t&7)^(r&7)
  const int srow = t >> 3;
  const int cg = (t & 7) ^ (srow & 7);
  const float* aqf[4];
  const unsigned short* bq[4];
#pragma unroll
  for (int q = 0; q < 4; ++q) {
    const int ridx = idxs[brow0 + srow + 64 * q];
    aqf[q] = tok + (size_t)ridx * K1 + cg * 8;
    bq[q] = W1b + (size_t)(bcol0 + srow + 64 * q) * K1 + cg * 8;
  }
  const int t8 = t * 8;

  floatx4 acc[8][4] = {};
  constexpr int NT = K1 / 64;

  float4 av[4][2];
  auto loadA = [&](int k0) {
#pragma unroll
    for (int q = 0; q < 4; ++q) {
      av[q][0] = *reinterpret_cast<const float4*>(aqf[q] + k0);
      av[q][1] = *reinterpret_cast<const float4*>(aqf[q] + k0 + 4);
    }
  };
  auto writeA = [&](int d) {
#pragma unroll
    for (int q = 0; q < 4; ++q) {
      ushortx8 u;
      u[0] = f2bf(av[q][0].x); u[1] = f2bf(av[q][0].y);
      u[2] = f2bf(av[q][0].z); u[3] = f2bf(av[q][0].w);
      u[4] = f2bf(av[q][1].x); u[5] = f2bf(av[q][1].y);
      u[6] = f2bf(av[q][1].z); u[7] = f2bf(av[q][1].w);
      *reinterpret_cast<ushortx8*>(&Asub[d][t8 + q * 4096]) = u;
    }
  };
  auto issueBq = [&](int d, int k0, int q) {
    switch (q) {  // literal LDS dest offsets (static indexing)
      case 0: gload_lds16(bq[0] + k0, &Bsub[d][t8]); break;
      case 1: gload_lds16(bq[1] + k0, &Bsub[d][t8 + 4096]); break;
      case 2: gload_lds16(bq[2] + k0, &Bsub[d][t8 + 8192]); break;
      default: gload_lds16(bq[3] + k0, &Bsub[d][t8 + 12288]); break;
    }
  };
  auto computeKS = [&](int cur, int ks) {
    const int sl = ((ks * 4 + kg2) ^ (fr & 7)) * 8;
    short8 bf[4];
#pragma unroll
    for (int j = 0; j < 4; ++j)
      bf[j] = *(const short8*)&Bsub[cur][(wn * 64 + j * 16 + fr) * 64 + sl];
    __builtin_amdgcn_s_setprio(1);
#pragma unroll
    for (int i = 0; i < 8; ++i) {
      const short8 af = *(const short8*)&Asub[cur][(wm * 128 + i * 16 + fr) * 64 + sl];
#pragma unroll
      for (int j = 0; j < 4; ++j)
        acc[i][j] = __builtin_amdgcn_mfma_f32_16x16x32_bf16(af, bf[j], acc[i][j], 0, 0, 0);
    }
    __builtin_amdgcn_s_setprio(0);
  };

  // prologue: tile 0. Order: av loads (8) then B (4); writeA's implicit
  // register wait drains av but leaves B(4) in flight.
  loadA(0);
  issueBq(0, 0, 0); issueBq(0, 0, 1); issueBq(0, 0, 2); issueBq(0, 0, 3);
  writeA(0);

#pragma unroll 1
  for (int tt = 0; tt < NT; ++tt) {
    const int cur = tt & 1;
    const int nbuf = cur ^ 1;
    const bool pf = (tt + 1 < NT);
    const int nk = (tt + 1) * 64;
    // boundary: my ds ops retired -> barrierA (nbuf safe to overwrite);
    // issue 1 next-B; counted vmcnt validates tile tt; barrierB (collective).
    asm volatile("s_waitcnt lgkmcnt(0)\ns_barrier" ::: "memory");
    if (pf) {
      issueBq(nbuf, nk, 0);
      asm volatile("s_waitcnt vmcnt(1)\ns_barrier" ::: "memory");
    } else {
      asm volatile("s_waitcnt vmcnt(0)\ns_barrier" ::: "memory");
    }
    if (pf) {
      loadA(nk);  // av for tile tt+1 (8 plain loads)
      issueBq(nbuf, nk, 1); issueBq(nbuf, nk, 2); issueBq(nbuf, nk, 3);
    }
    computeKS(cur, 0);
    if (pf) writeA(nbuf);  // implicit wait: av landed; B123 stay in flight
    computeKS(cur, 1);
  }

  // epilogue: C/D map col=lane&15, row=(lane>>4)*4+r
  const int er0 = brow0 + wm * 128 + kg2 * 4;
  const int ec0 = bcol0 + wn * 64 + fr;
#pragma unroll
  for (int j = 0; j < 4; ++j) {
    const float bv = b1[ec0 + j * 16];
#pragma unroll
    for (int i = 0; i < 8; ++i)
#pragma unroll
      for (int r = 0; r < 4; ++r) {
        float v = acc[i][j][r] + bv;
        v = 0.5f * v * (1.0f + erff(v * 0.70710678118654752f));
        hout[(size_t)(er0 + i * 16 + r) * N1 + (ec0 + j * 16)] = f2bf(v);
      }
  }
}

// GEMM2: out = h @ W2^T + b2 (fp32). r9 body; counted-vmcnt boundaries:
// stage0(2 ops) at boundary + rest(6) mid-iter; boundary waits vmcnt(2).
__global__ __launch_bounds__(512, 2) void gemm2_kernel(
    const unsigned short* __restrict__ A, const unsigned short* __restrict__ Bw,
    const float* __restrict__ bias, float* __restrict__ out) {
  __shared__ unsigned short Asub[2][16384];
  __shared__ unsigned short Bsub[2][16384];
  const int t = threadIdx.x;
  const int p = blockIdx.x;
  const int bid = (p & 7) * 32 + (p >> 3);
  const int bm = bid >> 2, bn = bid & 3;
  const int brow0 = bm * 256, bcol0 = bn * 256;
  const int lane = t & 63, w = t >> 6;
  const int wm = w >> 2, wn = w & 3;
  const int fr = lane & 15, kg2 = lane >> 4;

  const int srow = t >> 3;
  const int cg = (t & 7) ^ (srow & 7);
  const unsigned short* aq[4];
  const unsigned short* bq[4];
#pragma unroll
  for (int q = 0; q < 4; ++q) {
    aq[q] = A + (size_t)(brow0 + srow + 64 * q) * K2 + cg * 8;
    bq[q] = Bw + (size_t)(bcol0 + srow + 64 * q) * K2 + cg * 8;
  }
  const int t8 = t * 8;

  const int arow_sh = (wm * 128 + fr) * 64;
  const int brow_sh = (wn * 64 + fr) * 64;

  floatx4 acc[8][4] = {};
  constexpr int NT = K2 / 64;

  auto stage0 = [&](int d, int k0) {  // 2 ops
    gload_lds16(aq[0] + k0, &Asub[d][t8]);
    gload_lds16(bq[0] + k0, &Bsub[d][t8]);
  };
  auto stageRest = [&](int d, int k0) {  // 6 ops
#pragma unroll
    for (int q = 1; q < 4; ++q) {
      gload_lds16(aq[q] + k0, &Asub[d][t8 + q * 4096]);
      gload_lds16(bq[q] + k0, &Bsub[d][t8 + q * 4096]);
    }
  };
  auto compute = [&](int cur) {
#pragma unroll
    for (int ks = 0; ks < 2; ++ks) {
      const int sl = ((ks * 4 + kg2) ^ (fr & 7)) * 8;
      short8 bf[4];
#pragma unroll
      for (int j = 0; j < 4; ++j)
        bf[j] = *reinterpret_cast<const short8*>(&Bsub[cur][brow_sh + j * 1024 + sl]);
      __builtin_amdgcn_s_setprio(1);
#pragma unroll
      for (int i = 0; i < 8; ++i) {
        const short8 af = *reinterpret_cast<const short8*>(&Asub[cur][arow_sh + i * 1024 + sl]);
#pragma unroll
        for (int j = 0; j < 4; ++j)
          acc[i][j] = __builtin_amdgcn_mfma_f32_16x16x32_bf16(af, bf[j], acc[i][j], 0, 0, 0);
      }
      __builtin_amdgcn_s_setprio(0);
    }
  };

  // prologue: tile 0 fully issued (queue: 8 ops)
  stage0(0, 0);
  stageRest(0, 0);

#pragma unroll 1
  for (int tt = 0; tt < NT; ++tt) {
    const int cur = tt & 1;
    const int nbuf = cur ^ 1;
    const bool pf = (tt + 1 < NT);
    const int nk = (tt + 1) * 64;
    asm volatile("s_waitcnt lgkmcnt(0)\ns_barrier" ::: "memory");
    if (pf) {
      stage0(nbuf, nk);  // 2 newest
      asm volatile("s_waitcnt vmcnt(2)\ns_barrier" ::: "memory");
    } else {
      asm volatile("s_waitcnt vmcnt(0)\ns_barrier" ::: "memory");
    }
    if (pf) stageRest(nbuf, nk);  // 6 ops, in flight until next boundary
    compute(cur);
  }

  const int er0 = brow0 + wm * 128 + kg2 * 4;
  const int ec0 = bcol0 + wn * 64 + fr;
#pragma unroll
  for (int j = 0; j < 4; ++j) {
    const float bv = bias[ec0 + j * 16];
#pragma unroll
    for (int i = 0; i < 8; ++i)
#pragma unroll
      for (int r = 0; r < 4; ++r)
        out[(size_t)(er0 + i * 16 + r) * N2 + (ec0 + j * 16)] = acc[i][j][r] + bv;
  }
}

extern "C" void kernel_launch(void* const* d_in, const int* in_sizes, int n_in,
                              void* d_out, int out_size, void* d_ws, size_t ws_size,
                              hipStream_t stream) {
  const int* idxs = (const int*)d_in[0];
  const float* tok = (const float*)d_in[1];
  const float* W1 = (const float*)d_in[2];
  const float* b1 = (const float*)d_in[3];
  const float* W2 = (const float*)d_in[4];
  const float* b2 = (const float*)d_in[5];
  float* out = (float*)d_out;

  unsigned short* W1b = (unsigned short*)d_ws;                          // 4 MB
  unsigned short* W2b = (unsigned short*)((char*)d_ws + (4u << 20));    // 2 MB
  unsigned short* hbuf = (unsigned short*)((char*)d_ws + (6u << 20));   // 32 MB

  cvt_bf16_kernel<<<2048, 256, 0, stream>>>(W1, W1b, 524288);
  cvt_bf16_kernel<<<1024, 256, 0, stream>>>(W2, W2b, 262144);
  gemm1_fused_kernel<<<256, 512, 0, stream>>>(idxs, tok, W1b, b1, hbuf);
  gemm2_kernel<<<256, 512, 0, stream>>>(hbuf, W2b, b2, out);
}

// Round 14
// 157.432 us; speedup vs baseline: 1.4827x; 1.0231x over previous
//
#include <hip/hip_runtime.h>
#include <hip/hip_bf16.h>

// Round 14: identical to round 13 (container unresponsive; no signal).

typedef __attribute__((ext_vector_type(4))) float floatx4;
typedef __attribute__((ext_vector_type(8))) short short8;
typedef __attribute__((ext_vector_type(8))) unsigned short ushortx8;

#define K1 2048
#define N1 1024
#define K2 1024
#define N2 1024

__device__ __forceinline__ unsigned short f2bf(float f) {
  __hip_bfloat16 h = __float2bfloat16(f);
  return __builtin_bit_cast(unsigned short, h);
}

__device__ __forceinline__ void gload_lds16(const void* g, void* l) {
  __builtin_amdgcn_global_load_lds(
      (__attribute__((address_space(1))) void*)const_cast<void*>(g),
      (__attribute__((address_space(3))) void*)l, 16, 0, 0);
}

__global__ void cvt_bf16_kernel(const float* __restrict__ src,
                                unsigned short* __restrict__ dst, int n4) {
  int i = blockIdx.x * blockDim.x + threadIdx.x;
  if (i >= n4) return;
  float4 f = reinterpret_cast<const float4*>(src)[i];
  ushort4 o;
  o.x = f2bf(f.x); o.y = f2bf(f.y); o.z = f2bf(f.z); o.w = f2bf(f.w);
  reinterpret_cast<ushort4*>(dst)[i] = o;
}

// GEMM1 + fused gather: h = gelu(bf16(tok[idx]) @ W1^T + b1).
// 128x512 tile (A re-read factor 4 -> 2), BK=64, 8 waves each owning 128x64.
// r9 loop/sync verbatim. LDS 160KB: As 2x16KB (two 64-row subtiles), Bs
// 2x64KB (eight 64-row q-blocks); r9 slot-per-thread staging + XOR chunks.
__global__ __launch_bounds__(512, 2) void gemm1_fused_kernel(
    const int* __restrict__ idxs, const float* __restrict__ tok,
    const unsigned short* __restrict__ W1b, const float* __restrict__ b1,
    unsigned short* __restrict__ hout) {
  __shared__ unsigned short As[2][8192];   // [buf][sub 2][64 rows][8 slots][8]
  __shared__ unsigned short Bs[2][32768];  // [buf][q 8][64 rows][8 slots][8]
  const int t = threadIdx.x;
  const int p = blockIdx.x;
  const int bid = (p & 7) * 32 + (p >> 3);  // XCD owns contiguous range
  const int bm = bid >> 1, bn = bid & 1;    // adjacent bids share bm (A L2 hit)
  const int brow0 = bm * 128, bcol0 = bn * 512;
  const int lane = t & 63, w = t >> 6;
  const int wn = w;  // 8 waves across N; per-wave C = 128 x 64
  const int fr = lane & 15, kg2 = lane >> 4;

  // staging: srow = t>>3 (64 rows/subtile), slot = t&7, chunk = slot^(srow&7)
  const int srow = t >> 3;
  const int cg = (t & 7) ^ (srow & 7);
  const float* aqf[2];
  aqf[0] = tok + (size_t)idxs[brow0 + srow] * K1 + cg * 8;
  aqf[1] = tok + (size_t)idxs[brow0 + 64 + srow] * K1 + cg * 8;
  const unsigned short* bq = W1b + (size_t)(bcol0 + srow) * K1 + cg * 8;
  const int t8 = t * 8;

  floatx4 acc[8][4] = {};
  constexpr int NT = K1 / 64;  // 32

  float4 av[2][2];
  auto loadA = [&](int k0) {
#pragma unroll
    for (int s = 0; s < 2; ++s) {
      av[s][0] = *reinterpret_cast<const float4*>(aqf[s] + k0);
      av[s][1] = *reinterpret_cast<const float4*>(aqf[s] + k0 + 4);
    }
  };
  auto writeA = [&](int d) {
#pragma unroll
    for (int s = 0; s < 2; ++s) {
      ushortx8 u;
      u[0] = f2bf(av[s][0].x); u[1] = f2bf(av[s][0].y);
      u[2] = f2bf(av[s][0].z); u[3] = f2bf(av[s][0].w);
      u[4] = f2bf(av[s][1].x); u[5] = f2bf(av[s][1].y);
      u[6] = f2bf(av[s][1].z); u[7] = f2bf(av[s][1].w);
      *reinterpret_cast<ushortx8*>(&As[d][s * 4096 + t8]) = u;  // contiguous
    }
  };
  auto issueB = [&](int d, int k0) {
#pragma unroll
    for (int q = 0; q < 8; ++q)
      gload_lds16(bq + (size_t)q * 64 * K1 + k0, &Bs[d][q * 4096 + t8]);
  };
  auto computeKS = [&](int cur, int ks) {
    const int sl = ((ks * 4 + kg2) ^ (fr & 7)) * 8;
    short8 bf[4];
#pragma unroll
    for (int j = 0; j < 4; ++j)
      bf[j] = *(const short8*)&Bs[cur][wn * 4096 + (j * 16 + fr) * 64 + sl];
    __builtin_amdgcn_s_setprio(1);
#pragma unroll
    for (int i = 0; i < 8; ++i) {
      const short8 af = *(const short8*)
          &As[cur][(i >> 2) * 4096 + ((i & 3) * 16 + fr) * 64 + sl];
#pragma unroll
      for (int j = 0; j < 4; ++j)
        acc[i][j] = __builtin_amdgcn_mfma_f32_16x16x32_bf16(af, bf[j], acc[i][j], 0, 0, 0);
    }
    __builtin_amdgcn_s_setprio(0);
  };

  // prologue: tile 0
  loadA(0);
  issueB(0, 0);
  writeA(0);  // compiler waits the av loads
  asm volatile("s_waitcnt vmcnt(0) lgkmcnt(0)\ns_barrier" ::: "memory");

#pragma unroll 1
  for (int tt = 0; tt < NT; ++tt) {
    const int cur = tt & 1;
    const int nbuf = cur ^ 1;
    const bool pf = (tt + 1 < NT);
    const int nk = (tt + 1) * 64;
    if (pf) {
      loadA(nk);         // 4 fp32x4 reg loads in flight over ks0
      issueB(nbuf, nk);  // 8 gload_lds in flight until boundary
    }
    computeKS(cur, 0);
    if (pf) writeA(nbuf);  // cvt + ds_write under ks1's window
    computeKS(cur, 1);
    asm volatile("s_waitcnt vmcnt(0) lgkmcnt(0)\ns_barrier" ::: "memory");
  }

  // epilogue: bias + exact GELU -> bf16. C/D: col=lane&15, row=(lane>>4)*4+r
  const int er0 = brow0 + kg2 * 4;
  const int ec0 = bcol0 + wn * 64 + fr;
#pragma unroll
  for (int j = 0; j < 4; ++j) {
    const float bv = b1[ec0 + j * 16];
#pragma unroll
    for (int i = 0; i < 8; ++i)
#pragma unroll
      for (int r = 0; r < 4; ++r) {
        float v = acc[i][j][r] + bv;
        v = 0.5f * v * (1.0f + erff(v * 0.70710678118654752f));
        hout[(size_t)(er0 + i * 16 + r) * N1 + (ec0 + j * 16)] = f2bf(v);
      }
  }
}

// GEMM2: out = h @ W2^T + b2 (fp32). 128x512 tile, r9-g2 sync (vmcnt(10)).
__global__ __launch_bounds__(512, 2) void gemm2_kernel(
    const unsigned short* __restrict__ hb, const unsigned short* __restrict__ W2b,
    const float* __restrict__ b2, float* __restrict__ out) {
  __shared__ unsigned short As[2][8192];
  __shared__ unsigned short Bs[2][32768];
  const int t = threadIdx.x;
  const int p = blockIdx.x;
  const int bid = (p & 7) * 32 + (p >> 3);
  const int bm = bid >> 1, bn = bid & 1;
  const int brow0 = bm * 128, bcol0 = bn * 512;
  const int lane = t & 63, w = t >> 6;
  const int wn = w;
  const int fr = lane & 15, kg2 = lane >> 4;

  const int srow = t >> 3;
  const int cg = (t & 7) ^ (srow & 7);
  const unsigned short* aq[2];
  aq[0] = hb + (size_t)(brow0 + srow) * K2 + cg * 8;
  aq[1] = hb + (size_t)(brow0 + 64 + srow) * K2 + cg * 8;
  const unsigned short* bq = W2b + (size_t)(bcol0 + srow) * K2 + cg * 8;
  const int t8 = t * 8;

  floatx4 acc[8][4] = {};
  constexpr int NT = K2 / 64;  // 16

  auto stage = [&](int d, int k0) {  // 10 vmem ops
#pragma unroll
    for (int s = 0; s < 2; ++s)
      gload_lds16(aq[s] + k0, &As[d][s * 4096 + t8]);
#pragma unroll
    for (int q = 0; q < 8; ++q)
      gload_lds16(bq + (size_t)q * 64 * K2 + k0, &Bs[d][q * 4096 + t8]);
  };
  auto compute = [&](int cur) {
#pragma unroll
    for (int ks = 0; ks < 2; ++ks) {
      const int sl = ((ks * 4 + kg2) ^ (fr & 7)) * 8;
      short8 bf[4];
#pragma unroll
      for (int j = 0; j < 4; ++j)
        bf[j] = *(const short8*)&Bs[cur][wn * 4096 + (j * 16 + fr) * 64 + sl];
      __builtin_amdgcn_s_setprio(1);
#pragma unroll
      for (int i = 0; i < 8; ++i) {
        const short8 af = *(const short8*)
            &As[cur][(i >> 2) * 4096 + ((i & 3) * 16 + fr) * 64 + sl];
#pragma unroll
        for (int j = 0; j < 4; ++j)
          acc[i][j] = __builtin_amdgcn_mfma_f32_16x16x32_bf16(af, bf[j], acc[i][j], 0, 0, 0);
      }
      __builtin_amdgcn_s_setprio(0);
    }
  };

  stage(0, 0);
#pragma unroll 1
  for (int it = 0; it < NT - 1; ++it) {
    const int cur = it & 1;
    stage(cur ^ 1, (it + 1) * 64);
    asm volatile("s_waitcnt vmcnt(10)\ns_barrier" ::: "memory");
    compute(cur);
    asm volatile("s_waitcnt lgkmcnt(0)\ns_barrier" ::: "memory");
  }
  asm volatile("s_waitcnt vmcnt(0)\ns_barrier" ::: "memory");
  compute((NT - 1) & 1);

  const int er0 = brow0 + kg2 * 4;
  const int ec0 = bcol0 + wn * 64 + fr;
#pragma unroll
  for (int j = 0; j < 4; ++j) {
    const float bv = b2[ec0 + j * 16];
#pragma unroll
    for (int i = 0; i < 8; ++i)
#pragma unroll
      for (int r = 0; r < 4; ++r)
        out[(size_t)(er0 + i * 16 + r) * N2 + (ec0 + j * 16)] = acc[i][j][r] + bv;
  }
}

extern "C" void kernel_launch(void* const* d_in, const int* in_sizes, int n_in,
                              void* d_out, int out_size, void* d_ws, size_t ws_size,
                              hipStream_t stream) {
  const int* idxs = (const int*)d_in[0];
  const float* tok = (const float*)d_in[1];
  const float* W1 = (const float*)d_in[2];
  const float* b1 = (const float*)d_in[3];
  const float* W2 = (const float*)d_in[4];
  const float* b2 = (const float*)d_in[5];
  float* out = (float*)d_out;

  unsigned short* W1b = (unsigned short*)d_ws;                          // 4 MB
  unsigned short* W2b = (unsigned short*)((char*)d_ws + (4u << 20));    // 2 MB
  unsigned short* hbuf = (unsigned short*)((char*)d_ws + (6u << 20));   // 32 MB

  cvt_bf16_kernel<<<2048, 256, 0, stream>>>(W1, W1b, 524288);
  cvt_bf16_kernel<<<1024, 256, 0, stream>>>(W2, W2b, 262144);
  gemm1_fused_kernel<<<256, 512, 0, stream>>>(idxs, tok, W1b, b1, hbuf);
  gemm2_kernel<<<256, 512, 0, stream>>>(hbuf, W2b, b2, out);
}

// Round 17
// 140.895 us; speedup vs baseline: 1.6568x; 1.1174x over previous
//
#include <hip/hip_runtime.h>
#include <hip/hip_bf16.h>

typedef __attribute__((ext_vector_type(4))) float floatx4;
typedef __attribute__((ext_vector_type(8))) short short8;
typedef __attribute__((ext_vector_type(8))) unsigned short ushortx8;

#define K1 2048
#define N1 1024
#define K2 1024
#define N2 1024

__device__ __forceinline__ unsigned short f2bf(float f) {
  __hip_bfloat16 h = __float2bfloat16(f);
  return __builtin_bit_cast(unsigned short, h);
}

__device__ __forceinline__ void gload_lds16(const void* g, void* l) {
  __builtin_amdgcn_global_load_lds(
      (__attribute__((address_space(1))) void*)const_cast<void*>(g),
      (__attribute__((address_space(3))) void*)l, 16, 0, 0);
}

// merged W1+W2 fp32->bf16 convert
__global__ __launch_bounds__(256) void cvt2_kernel(
    const float* __restrict__ W1, const float* __restrict__ W2,
    unsigned short* __restrict__ W1b, unsigned short* __restrict__ W2b) {
  int i = blockIdx.x * blockDim.x + threadIdx.x;
  const float* src;
  unsigned short* dst;
  if (i < 524288) {
    src = (const float*)&reinterpret_cast<const float4*>(W1)[i];
    dst = (unsigned short*)&reinterpret_cast<ushort4*>(W1b)[i];
  } else {
    int k = i - 524288;
    if (k >= 262144) return;
    src = (const float*)&reinterpret_cast<const float4*>(W2)[k];
    dst = (unsigned short*)&reinterpret_cast<ushort4*>(W2b)[k];
  }
  float4 f = *reinterpret_cast<const float4*>(src);
  ushort4 o;
  o.x = f2bf(f.x); o.y = f2bf(f.y); o.z = f2bf(f.z); o.w = f2bf(f.w);
  *reinterpret_cast<ushort4*>(dst) = o;
}

// GEMM1 + fused gather: h = gelu(bf16(tok[idx]) @ W1^T + b1).
// K-loop = r9 verbatim INCLUDING the prologue drain+barrier (r15/r16 dropped
// it -> first-iteration LDS race -> NaN). LDS-transpose epilogue, 16 passes.
__global__ __launch_bounds__(512, 2) void gemm1_fused_kernel(
    const int* __restrict__ idxs, const float* __restrict__ tok,
    const unsigned short* __restrict__ W1b, const float* __restrict__ b1,
    unsigned short* __restrict__ hout) {
  __shared__ unsigned short S[65536];  // loop: A 2x16384 | B 2x16384; epi: 8x8192
  const int t = threadIdx.x;
  const int p = blockIdx.x;
  const int bid = (p & 7) * 32 + (p >> 3);  // XCD owns contiguous bm range
  const int bm = bid >> 2, bn = bid & 3;
  const int brow0 = bm * 256, bcol0 = bn * 256;
  const int lane = t & 63, w = t >> 6;
  const int wm = w >> 2, wn = w & 3;  // per-wave C: 128x64
  const int fr = lane & 15, kg2 = lane >> 4;

  const int srow = t >> 3;
  const int cg = (t & 7) ^ (srow & 7);
  const float* aqf[4];
  const unsigned short* bq[4];
#pragma unroll
  for (int q = 0; q < 4; ++q) {
    const int ridx = idxs[brow0 + srow + 64 * q];
    aqf[q] = tok + (size_t)ridx * K1 + cg * 8;
    bq[q] = W1b + (size_t)(bcol0 + srow + 64 * q) * K1 + cg * 8;
  }
  const int t8 = t * 8;

  floatx4 acc[8][4] = {};
  constexpr int NT = K1 / 64;

  float4 av[4][2];
  auto loadA = [&](int k0) {
#pragma unroll
    for (int q = 0; q < 4; ++q) {
      av[q][0] = *reinterpret_cast<const float4*>(aqf[q] + k0);
      av[q][1] = *reinterpret_cast<const float4*>(aqf[q] + k0 + 4);
    }
  };
  auto writeA = [&](int d) {
#pragma unroll
    for (int q = 0; q < 4; ++q) {
      ushortx8 u;
      u[0] = f2bf(av[q][0].x); u[1] = f2bf(av[q][0].y);
      u[2] = f2bf(av[q][0].z); u[3] = f2bf(av[q][0].w);
      u[4] = f2bf(av[q][1].x); u[5] = f2bf(av[q][1].y);
      u[6] = f2bf(av[q][1].z); u[7] = f2bf(av[q][1].w);
      *reinterpret_cast<ushortx8*>(&S[d * 16384 + t8 + q * 4096]) = u;
    }
  };
  auto issueB = [&](int d, int k0) {
#pragma unroll
    for (int q = 0; q < 4; ++q)
      gload_lds16(bq[q] + k0, &S[32768 + d * 16384 + t8 + q * 4096]);
  };
  auto computeKS = [&](int cur, int ks) {
    const int sl = ((ks * 4 + kg2) ^ (fr & 7)) * 8;
    short8 bf[4];
#pragma unroll
    for (int j = 0; j < 4; ++j)
      bf[j] = *(const short8*)&S[32768 + cur * 16384 + (wn * 64 + j * 16 + fr) * 64 + sl];
    __builtin_amdgcn_s_setprio(1);
#pragma unroll
    for (int i = 0; i < 8; ++i) {
      const short8 af = *(const short8*)&S[cur * 16384 + (wm * 128 + i * 16 + fr) * 64 + sl];
#pragma unroll
      for (int j = 0; j < 4; ++j)
        acc[i][j] = __builtin_amdgcn_mfma_f32_16x16x32_bf16(af, bf[j], acc[i][j], 0, 0, 0);
    }
    __builtin_amdgcn_s_setprio(0);
  };

  // prologue: stage tile 0 and WAIT (r15/r16 regression: this drain+barrier
  // was missing -> tt=0 read un-landed B staging -> NaN).
  loadA(0);
  issueB(0, 0);
  writeA(0);
  asm volatile("s_waitcnt vmcnt(0) lgkmcnt(0)\ns_barrier" ::: "memory");

#pragma unroll 1
  for (int tt = 0; tt < NT; ++tt) {
    const int cur = tt & 1;
    const int nbuf = cur ^ 1;
    const bool pf = (tt + 1 < NT);
    const int nk = (tt + 1) * 64;
    if (pf) {
      loadA(nk);
      issueB(nbuf, nk);
    }
    computeKS(cur, 0);
    if (pf) writeA(nbuf);
    computeKS(cur, 1);
    asm volatile("s_waitcnt vmcnt(0) lgkmcnt(0)\ns_barrier" ::: "memory");
  }
  // loop ended with full drain + barrier -> LDS free for epilogue reuse.

  // epilogue: bias + exact GELU -> LDS (chunk-XOR swizzled) -> coalesced store
  const int ec0 = bcol0 + wn * 64 + fr;
  float bv[4];
#pragma unroll
  for (int j = 0; j < 4; ++j) bv[j] = b1[ec0 + j * 16];
  unsigned short* Wl = S + w * 8192;  // this wave's 128x64 region
#pragma unroll
  for (int i = 0; i < 8; ++i)
#pragma unroll
    for (int j = 0; j < 4; ++j)
#pragma unroll
      for (int r = 0; r < 4; ++r) {
        float v = acc[i][j][r] + bv[j];
        v = 0.5f * v * (1.0f + erff(v * 0.70710678118654752f));
        const int row = i * 16 + kg2 * 4 + r;
        const int col = (j * 16 + fr) ^ (kg2 << 3);  // chunk-XOR swizzle
        Wl[row * 64 + col] = f2bf(v);
      }
  asm volatile("s_waitcnt lgkmcnt(0)" ::: "memory");
#pragma unroll
  for (int pass = 0; pass < 16; ++pass) {  // 16 passes x 8 rows = 128 rows
    const int wr = pass * 8 + (lane >> 3);
    const int ch = (lane & 7) ^ ((wr >> 2) & 3);  // unswizzle chunk
    const short8 v8 = *(const short8*)&Wl[wr * 64 + ch * 8];
    *reinterpret_cast<short8*>(
        &hout[(size_t)(brow0 + wm * 128 + wr) * N1 + bcol0 + wn * 64 + (lane & 7) * 8]) = v8;
  }
}

// GEMM2: out = h @ W2^T + b2 (fp32). K-loop = r9-g2 verbatim; LDS-transpose
// epilogue in two 64-row halves (16 passes x 4 rows each).
__global__ __launch_bounds__(512, 2) void gemm2_kernel(
    const unsigned short* __restrict__ A, const unsigned short* __restrict__ Bw,
    const float* __restrict__ bias, float* __restrict__ out) {
  __shared__ unsigned short S[65536];
  const int t = threadIdx.x;
  const int p = blockIdx.x;
  const int bid = (p & 7) * 32 + (p >> 3);
  const int bm = bid >> 2, bn = bid & 3;
  const int brow0 = bm * 256, bcol0 = bn * 256;
  const int lane = t & 63, w = t >> 6;
  const int wm = w >> 2, wn = w & 3;
  const int fr = lane & 15, kg2 = lane >> 4;

  const int srow = t >> 3;
  const int cg = (t & 7) ^ (srow & 7);
  const unsigned short* aq[4];
  const unsigned short* bq[4];
#pragma unroll
  for (int q = 0; q < 4; ++q) {
    aq[q] = A + (size_t)(brow0 + srow + 64 * q) * K2 + cg * 8;
    bq[q] = Bw + (size_t)(bcol0 + srow + 64 * q) * K2 + cg * 8;
  }
  const int t8 = t * 8;

  floatx4 acc[8][4] = {};
  constexpr int NT = K2 / 64;

  auto stage = [&](int d, int k0) {
#pragma unroll
    for (int q = 0; q < 4; ++q) {
      gload_lds16(aq[q] + k0, &S[d * 16384 + t8 + q * 4096]);
      gload_lds16(bq[q] + k0, &S[32768 + d * 16384 + t8 + q * 4096]);
    }
  };
  auto compute = [&](int cur) {
#pragma unroll
    for (int ks = 0; ks < 2; ++ks) {
      const int sl = ((ks * 4 + kg2) ^ (fr & 7)) * 8;
      short8 bf[4];
#pragma unroll
      for (int j = 0; j < 4; ++j)
        bf[j] = *(const short8*)&S[32768 + cur * 16384 + (wn * 64 + j * 16 + fr) * 64 + sl];
      __builtin_amdgcn_s_setprio(1);
#pragma unroll
      for (int i = 0; i < 8; ++i) {
        const short8 af = *(const short8*)&S[cur * 16384 + (wm * 128 + i * 16 + fr) * 64 + sl];
#pragma unroll
        for (int j = 0; j < 4; ++j)
          acc[i][j] = __builtin_amdgcn_mfma_f32_16x16x32_bf16(af, bf[j], acc[i][j], 0, 0, 0);
      }
      __builtin_amdgcn_s_setprio(0);
    }
  };

  stage(0, 0);
#pragma unroll 1
  for (int it = 0; it < NT - 1; ++it) {
    const int cur = it & 1;
    stage(cur ^ 1, (it + 1) * 64);
    asm volatile("s_waitcnt vmcnt(8)\ns_barrier" ::: "memory");
    compute(cur);
    asm volatile("s_waitcnt lgkmcnt(0)\ns_barrier" ::: "memory");
  }
  asm volatile("s_waitcnt vmcnt(0)\ns_barrier" ::: "memory");
  compute((NT - 1) & 1);
  // other waves may still be reading LDS fragments -> drain + barrier first
  asm volatile("s_waitcnt lgkmcnt(0)\ns_barrier" ::: "memory");

  const int ec0 = bcol0 + wn * 64 + fr;
  float bv[4];
#pragma unroll
  for (int j = 0; j < 4; ++j) bv[j] = bias[ec0 + j * 16];
  float* Wf = reinterpret_cast<float*>(S) + w * 4096;  // 64x64 fp32 per half
#pragma unroll
  for (int ih = 0; ih < 2; ++ih) {
#pragma unroll
    for (int i4 = 0; i4 < 4; ++i4)
#pragma unroll
      for (int j = 0; j < 4; ++j)
#pragma unroll
        for (int r = 0; r < 4; ++r) {
          const int row = i4 * 16 + kg2 * 4 + r;
          const int col = (j * 16 + fr) ^ (kg2 << 2);  // float4-chunk XOR
          Wf[row * 64 + col] = acc[ih * 4 + i4][j][r] + bv[j];
        }
    asm volatile("s_waitcnt lgkmcnt(0)" ::: "memory");
#pragma unroll
    for (int pass = 0; pass < 16; ++pass) {  // 16 passes x 4 rows = 64 rows
      const int wr = pass * 4 + (lane >> 4);
      const int ch = (lane & 15) ^ ((wr >> 2) & 3);
      const floatx4 v4 = *(const floatx4*)&Wf[wr * 64 + ch * 4];
      *reinterpret_cast<floatx4*>(
          &out[(size_t)(brow0 + wm * 128 + ih * 64 + wr) * N2 + bcol0 + wn * 64 +
               (lane & 15) * 4]) = v4;
    }
    if (ih == 0)  // reuse region for second half; own-wave RAW only
      asm volatile("s_waitcnt lgkmcnt(0)" ::: "memory");
  }
}

extern "C" void kernel_launch(void* const* d_in, const int* in_sizes, int n_in,
                              void* d_out, int out_size, void* d_ws, size_t ws_size,
                              hipStream_t stream) {
  const int* idxs = (const int*)d_in[0];
  const float* tok = (const float*)d_in[1];
  const float* W1 = (const float*)d_in[2];
  const float* b1 = (const float*)d_in[3];
  const float* W2 = (const float*)d_in[4];
  const float* b2 = (const float*)d_in[5];
  float* out = (float*)d_out;

  unsigned short* W1b = (unsigned short*)d_ws;                          // 4 MB
  unsigned short* W2b = (unsigned short*)((char*)d_ws + (4u << 20));    // 2 MB
  unsigned short* hbuf = (unsigned short*)((char*)d_ws + (6u << 20));   // 32 MB

  cvt2_kernel<<<3072, 256, 0, stream>>>(W1, W2, W1b, W2b);
  gemm1_fused_kernel<<<256, 512, 0, stream>>>(idxs, tok, W1b, b1, hbuf);
  gemm2_kernel<<<256, 512, 0, stream>>>(hbuf, W2b, b2, out);
}